// Round 9
// baseline (378.682 us; speedup 1.0000x reference)
//
#include <hip/hip_runtime.h>
#include <hip/hip_bf16.h>

// Problem sizes (fixed by the reference)
#define B_ 8192
#define D_ 512
#define H_ 1024
#define S_ 4096
#define Y_ 256

// Output element offsets (fp32 elements) in return order:
// mu, Z, soft_prob, soft_prob_y, hard_prob, batch_y   (d_out is FLOAT32)
constexpr size_t O_MU    = 0;
constexpr size_t O_Z     = (size_t)B_ * D_;
constexpr size_t O_SOFT  = O_Z + (size_t)B_ * D_;
constexpr size_t O_SOFTY = O_SOFT + (size_t)B_ * S_;
constexpr size_t O_HARD  = O_SOFTY + (size_t)B_ * Y_;
constexpr size_t O_BY    = O_HARD + (size_t)B_ * S_;

typedef _Float16 half8 __attribute__((ext_vector_type(8)));
typedef float f32x4 __attribute__((ext_vector_type(4)));
typedef unsigned int u32;

// ---------------------------------------------------------------------------
// helpers
// ---------------------------------------------------------------------------
__device__ __forceinline__ void gload16(const void* g, void* l) {
  __builtin_amdgcn_global_load_lds((const __attribute__((address_space(1))) u32*)g,
                                   (__attribute__((address_space(3))) u32*)l,
                                   16, 0, 0);
}

__device__ __forceinline__ void split2(float x, _Float16& h, _Float16& l) {
  _Float16 hi = (_Float16)x;
  h = hi;
  l = (_Float16)((x - (float)hi) * 2048.0f);  // lo scaled by 2^11 (avoid denormals)
}

__device__ __forceinline__ float blockMax(float v, float* sh) {
#pragma unroll
  for (int o = 32; o; o >>= 1) v = fmaxf(v, __shfl_xor(v, o));
  if ((threadIdx.x & 63) == 0) sh[threadIdx.x >> 6] = v;
  __syncthreads();
  float r = fmaxf(fmaxf(sh[0], sh[1]), fmaxf(sh[2], sh[3]));
  __syncthreads();
  return r;
}

__device__ __forceinline__ float blockSum(float v, float* sh) {
#pragma unroll
  for (int o = 32; o; o >>= 1) v += __shfl_xor(v, o);
  if ((threadIdx.x & 63) == 0) sh[threadIdx.x >> 6] = v;
  __syncthreads();
  float r = (sh[0] + sh[1]) + (sh[2] + sh[3]);
  __syncthreads();
  return r;
}

// max value, ties -> smallest index (replicates jnp.argmax first-occurrence)
__device__ __forceinline__ void blockArgmax(float& v, int& i, float* shf, int* shi) {
#pragma unroll
  for (int o = 32; o; o >>= 1) {
    float v2 = __shfl_xor(v, o);
    int   i2 = __shfl_xor(i, o);
    if (v2 > v || (v2 == v && i2 < i)) { v = v2; i = i2; }
  }
  if ((threadIdx.x & 63) == 0) { shf[threadIdx.x >> 6] = v; shi[threadIdx.x >> 6] = i; }
  __syncthreads();
  float bv = shf[0]; int bi = shi[0];
#pragma unroll
  for (int k = 1; k < 4; ++k) {
    float v2 = shf[k]; int i2 = shi[k];
    if (v2 > bv || (v2 == bv && i2 < bi)) { bv = v2; bi = i2; }
  }
  v = bv; i = bi;
  __syncthreads();
}

// ---------------------------------------------------------------------------
// prep segments (device functions used from two dispatches)
// ---------------------------------------------------------------------------
__device__ void seg_split(const float* __restrict__ s, _Float16* __restrict__ h,
                          _Float16* __restrict__ l, size_t n, int b, int nb) {
  size_t i = (size_t)b * 256 + threadIdx.x;
  size_t st = (size_t)nb * 256;
  for (; i < n; i += st) { _Float16 hi, lo; split2(s[i], hi, lo); h[i] = hi; l[i] = lo; }
}

__device__ void seg_tsplit(const float* __restrict__ W, int K, int N,
                           _Float16* __restrict__ th, _Float16* __restrict__ tl,
                           int tile, float (*tl_lds)[33]) {
  int ntn = N / 32;
  int nb = (tile % ntn) * 32, kb = (tile / ntn) * 32;
  int tx = threadIdx.x & 31, ty = threadIdx.x >> 5;  // 32 x 8
  for (int r = ty; r < 32; r += 8)
    tl_lds[r][tx] = W[(size_t)(kb + r) * N + nb + tx];
  __syncthreads();
  for (int r = ty; r < 32; r += 8) {
    float x = tl_lds[tx][r];            // = W[kb+tx][nb+r]
    size_t o = (size_t)(nb + r) * K + kb + tx;
    _Float16 hi, lo; split2(x, hi, lo);
    th[o] = hi; tl[o] = lo;
  }
}

__device__ void seg_rownorm(const float* __restrict__ A, int K, float* __restrict__ out,
                            int tile) {
  int w = threadIdx.x >> 6, lane = threadIdx.x & 63;
  int row = tile * 4 + w;
  const float* a = A + (size_t)row * K;
  float s = 0.f;
  for (int k = lane; k < K; k += 64) { float x = a[k]; s += x * x; }
#pragma unroll
  for (int o = 32; o; o >>= 1) s += __shfl_xor(s, o);
  if (lane == 0) out[row] = s;
}

// prep dispatch: X split + weight transpose-splits (needed by L1 immediately)
__global__ __launch_bounds__(256) void prep_kernel(
    const float* __restrict__ X, const float* __restrict__ W1, const float* __restrict__ Ws1,
    const float* __restrict__ W2, const float* __restrict__ Ws2,
    _Float16* XH, _Float16* XL,
    _Float16* W1CH, _Float16* W1CL, _Float16* W2CH, _Float16* W2CL) {
  __shared__ float tile[32][33];
  int b = blockIdx.x;
  if (b < 512)       seg_split(X, XH, XL, (size_t)B_ * D_, b, 512);
  else if (b < 1024) seg_tsplit(W1,  D_, H_, W1CH, W1CL, b - 512, tile);
  else if (b < 1536) seg_tsplit(Ws1, D_, H_, W1CH + (size_t)H_ * D_,
                                W1CL + (size_t)H_ * D_, b - 1024, tile);
  else if (b < 2048) seg_tsplit(W2,  H_, D_, W2CH, W2CL, b - 1536, tile);
  else               seg_tsplit(Ws2, H_, D_, W2CH + (size_t)D_ * H_,
                                W2CL + (size_t)D_ * H_, b - 2048, tile);
}

// ---------------------------------------------------------------------------
// split-fp16 MFMA GEMM core: C[m][n] = sum_k A[m][k] * Bmat[n][k]  (NT)
// A ~ Ah + Al/2048, B ~ Bh + Bl/2048; acc = hh; accc = h*l + l*h (scale 2^11)
// 128x128 tile, BK=64, 4 waves; wave w stages LDS tile w (Ah/Al/Bh/Bl) via
// global_load_lds (16B) with XOR source-swizzle; reads undo the swizzle.
// (Engine verified: rounds 1/2/3 bit-identical; passing since round 6.)
// EPI 0: relu(c + cat-bias) -> split fp16 pair
// EPI 1: c + cat-bias -> f32
// EPI 2: 2c - rown[m] - coln[n] -> f32          (-||a-b||^2 logits)
// ---------------------------------------------------------------------------
template <int EPI>
__device__ __forceinline__ void gemm_core(
    _Float16* lds, int bx, int by,
    const _Float16* __restrict__ Ah, const _Float16* __restrict__ Al,
    const _Float16* __restrict__ Bh, const _Float16* __restrict__ Bl,
    int N, int K, int lda, int ldc, int nsplit, int aoff2,
    const float* __restrict__ bias, const float* __restrict__ bias2,
    float* __restrict__ Cf, _Float16* __restrict__ Ch, _Float16* __restrict__ Cl,
    const float* __restrict__ rown, const float* __restrict__ coln) {
  const int tid = threadIdx.x;
  const int w = tid >> 6, lane = tid & 63;
  const int m0 = by * 128, n0 = bx * 128;
  const int g4 = lane >> 4, l15 = lane & 15;
  const int ln3 = lane >> 3, l7 = lane & 7;
  const int wsx = l7 ^ ln3;  // source-side XOR swizzle (16B units within 128B row)
  const int strideA = (w < 2) ? lda : K;
  const size_t laneoff = (size_t)ln3 * strideA + (size_t)wsx * 8;
  const int ashift = (n0 >= nsplit) ? aoff2 : 0;  // block-uniform

  const _Float16* stage_src =
      (w == 0) ? (Ah + (size_t)m0 * lda + ashift) :
      (w == 1) ? (Al + (size_t)m0 * lda + ashift) :
      (w == 2) ? (Bh + (size_t)n0 * K) : (Bl + (size_t)n0 * K);
  _Float16* stage_dst = &lds[w * 8192];

  const int wm = w >> 1, wn = w & 1;  // wave quadrant (64x64)

  f32x4 acc[4][4] = {};
  f32x4 accc[4][4] = {};

  for (int k0 = 0; k0 < K; k0 += 64) {
    const _Float16* sp = stage_src + k0 + laneoff;
#pragma unroll
    for (int q = 0; q < 16; ++q)
      gload16(sp + (size_t)q * 8 * strideA, stage_dst + q * 512);
    __syncthreads();

#pragma unroll
    for (int kk = 0; kk < 2; ++kk) {
      half8 ah[4], al[4], bh[4], bl[4];
#pragma unroll
      for (int mi = 0; mi < 4; ++mi) {
        int row = wm * 64 + mi * 16 + l15;
        int off = row * 64 + (((kk * 4 + g4) ^ (l15 & 7)) * 8);
        ah[mi] = *(const half8*)&lds[off];
        al[mi] = *(const half8*)&lds[8192 + off];
      }
#pragma unroll
      for (int ni = 0; ni < 4; ++ni) {
        int row = wn * 64 + ni * 16 + l15;
        int off = row * 64 + (((kk * 4 + g4) ^ (l15 & 7)) * 8);
        bh[ni] = *(const half8*)&lds[16384 + off];
        bl[ni] = *(const half8*)&lds[24576 + off];
      }
#pragma unroll
      for (int mi = 0; mi < 4; ++mi)
#pragma unroll
        for (int ni = 0; ni < 4; ++ni) {
          acc[mi][ni]  = __builtin_amdgcn_mfma_f32_16x16x32_f16(ah[mi], bh[ni], acc[mi][ni], 0, 0, 0);
          accc[mi][ni] = __builtin_amdgcn_mfma_f32_16x16x32_f16(ah[mi], bl[ni], accc[mi][ni], 0, 0, 0);
          accc[mi][ni] = __builtin_amdgcn_mfma_f32_16x16x32_f16(al[mi], bh[ni], accc[mi][ni], 0, 0, 0);
        }
    }
    __syncthreads();
  }

#pragma unroll
  for (int mi = 0; mi < 4; ++mi)
#pragma unroll
    for (int ni = 0; ni < 4; ++ni)
#pragma unroll
      for (int r = 0; r < 4; ++r) {
        int m = m0 + wm * 64 + mi * 16 + g4 * 4 + r;
        int n = n0 + wn * 64 + ni * 16 + l15;
        float c = acc[mi][ni][r] + accc[mi][ni][r] * (1.0f / 2048.0f);
        size_t idx = (size_t)m * ldc + n;
        if (EPI == 0) {
          float bv = (n < nsplit) ? bias[n] : bias2[n - nsplit];
          c = fmaxf(c + bv, 0.0f);
          _Float16 hi, lo; split2(c, hi, lo);
          Ch[idx] = hi; Cl[idx] = lo;
        } else if (EPI == 1) {
          float bv = (n < nsplit) ? bias[n] : bias2[n - nsplit];
          Cf[idx] = c + bv;
        } else {
          Cf[idx] = 2.0f * c - rown[m] - coln[n];
        }
      }
}

// L1 GEMM (N=2048 cat of both heads) + absorbed prep-B tail blocks:
// mu_s/mu_y splits + codebook rownorms run co-resident with the MFMA blocks
// (their outputs are first consumed 3 dispatches later by k_dist).
__global__ __launch_bounds__(256, 2) void k_l1(
    const _Float16* __restrict__ XH, const _Float16* __restrict__ XL,
    const _Float16* __restrict__ W1CH, const _Float16* __restrict__ W1CL,
    const float* __restrict__ b1, const float* __restrict__ bs1,
    _Float16* H1H, _Float16* H1L,
    const float* __restrict__ mu_s, const float* __restrict__ mu_y,
    _Float16* MSH, _Float16* MSL, _Float16* MYH, _Float16* MYL,
    float* CS2, float* CY2) {
  __shared__ _Float16 lds[4 * 8192];
  int b = blockIdx.x;
  if (b < 1024) {
    gemm_core<0>(lds, b & 15, b >> 4, XH, XL, W1CH, W1CL,
                 2 * H_, D_, D_, 2 * H_, H_, 0, b1, bs1,
                 nullptr, H1H, H1L, nullptr, nullptr);
  } else {
    float (*tile)[33] = (float(*)[33])lds;
    int c = b - 1024;
    if (c < 256)        seg_split(mu_s, MSH, MSL, (size_t)S_ * D_, c, 256);
    else if (c < 272)   seg_split(mu_y, MYH, MYL, (size_t)Y_ * D_, c - 256, 16);
    else if (c < 1296)  seg_rownorm(mu_s, D_, CS2, c - 272);
    else                seg_rownorm(mu_y, D_, CY2, c - 1296);
    (void)tile;
  }
}

// L2 GEMM (N=1024 cat mu|ps; A-column switch at nsplit)
__global__ __launch_bounds__(256, 2) void k_l2(
    const _Float16* __restrict__ H1H, const _Float16* __restrict__ H1L,
    const _Float16* __restrict__ W2CH, const _Float16* __restrict__ W2CL,
    const float* __restrict__ b2, const float* __restrict__ bs2,
    float* MPS) {
  __shared__ _Float16 lds[4 * 8192];
  int b = blockIdx.x;
  gemm_core<1>(lds, b & 7, b >> 3, H1H, H1L, W2CH, W2CL,
               2 * D_, H_, 2 * H_, 2 * D_, D_, H_, b2, bs2,
               MPS, nullptr, nullptr, nullptr, nullptr);
}

// merged dist GEMM: blocks [0,2048) fine logits -> out soft slot;
// blocks [2048,2240) coarse logits (A = contiguous [Z; mu_s], rown = [Z2|CS2])
__global__ __launch_bounds__(256, 2) void k_dist(
    const _Float16* __restrict__ ZH, const _Float16* __restrict__ ZL,
    const _Float16* __restrict__ MSH, const _Float16* __restrict__ MSL,
    const _Float16* __restrict__ MYH, const _Float16* __restrict__ MYL,
    float* LOGITS, float* LZY,
    const float* __restrict__ Z2, const float* __restrict__ CS2,
    const float* __restrict__ CY2) {
  __shared__ _Float16 lds[4 * 8192];
  int b = blockIdx.x;
  if (b < 2048) {
    gemm_core<2>(lds, b & 31, b >> 5, ZH, ZL, MSH, MSL,
                 S_, D_, D_, S_, 1 << 30, 0, nullptr, nullptr,
                 LOGITS, nullptr, nullptr, Z2, CS2);
  } else {
    int c = b - 2048;
    gemm_core<2>(lds, c & 1, c >> 1, ZH, ZL, MYH, MYL,
                 Y_, D_, D_, Y_, 1 << 30, 0, nullptr, nullptr,
                 LZY, nullptr, nullptr, Z2, CY2);
  }
}

// ---------------------------------------------------------------------------
// Z = mu + softplus(ps)*eps ; MPS holds [mu | ps] per row (ld 1024).
// writes mu,Z (fp32 out), Z split pair, ||Z||^2
// ---------------------------------------------------------------------------
__global__ __launch_bounds__(256) void kz_kernel(const float* __restrict__ MPS,
                                                 const float* __restrict__ eps,
                                                 float* __restrict__ out,
                                                 _Float16* __restrict__ Zh,
                                                 _Float16* __restrict__ Zl,
                                                 float* __restrict__ z2) {
  __shared__ float sh[4];
  int row = blockIdx.x, t = threadIdx.x;
  float s = 0.f;
  for (int j = t; j < D_; j += 256) {
    size_t idx = (size_t)row * D_ + j;
    float m = MPS[(size_t)row * 1024 + j];
    float p = MPS[(size_t)row * 1024 + 512 + j];
    float e = eps[idx];
    float sp = fmaxf(p, 0.f) + log1pf(expf(-fabsf(p)));  // stable softplus
    float z = m + sp * e;
    out[O_MU + idx] = m;
    out[O_Z + idx] = z;
    _Float16 hi, lo; split2(z, hi, lo);
    Zh[idx] = hi; Zl[idx] = lo;
    s += z * z;
  }
#pragma unroll
  for (int o = 32; o; o >>= 1) s += __shfl_xor(s, o);
  if ((t & 63) == 0) sh[t >> 6] = s;
  __syncthreads();
  if (t == 0) z2[row] = (sh[0] + sh[1]) + (sh[2] + sh[3]);
}

// ---------------------------------------------------------------------------
// fused fine+coarse routing (one block per batch row):
//  - fine: double softmax + gumbel + argmax over S=4096; logits read from
//    out[O_SOFT] into registers, same slots overwritten with final probs.
//  - coarse: ky logic as tail (Y=256=blockDim), using the in-block fine idx.
// ---------------------------------------------------------------------------
__global__ __launch_bounds__(256) void ks_kernel(const float* __restrict__ us,
                                                 const float* __restrict__ lzy,
                                                 const float* __restrict__ lsy,
                                                 const float* __restrict__ uy,
                                                 float* __restrict__ out) {
  __shared__ float shf[4];
  __shared__ int shi[4];
  int row = blockIdx.x, t = threadIdx.x;
  const float4* l4 = (const float4*)(out + O_SOFT + (size_t)row * S_) + t * 4;
  const float4* u4 = (const float4*)(us + (size_t)row * S_) + t * 4;

  float v[16];
#pragma unroll
  for (int q = 0; q < 4; ++q) {
    float4 x = l4[q];
    v[q * 4 + 0] = x.x; v[q * 4 + 1] = x.y; v[q * 4 + 2] = x.z; v[q * 4 + 3] = x.w;
  }
  float m1 = -3.4e38f;
#pragma unroll
  for (int k = 0; k < 16; ++k) m1 = fmaxf(m1, v[k]);
  m1 = blockMax(m1, shf);
  float s1 = 0.f;
#pragma unroll
  for (int k = 0; k < 16; ++k) { v[k] = __expf(v[k] - m1); s1 += v[k]; }
  s1 = blockSum(s1, shf);
  float is1 = 1.0f / s1;
  float m2 = -3.4e38f;
#pragma unroll
  for (int q = 0; q < 4; ++q) {
    float4 uu = u4[q];
    float ua[4] = {uu.x, uu.y, uu.z, uu.w};
#pragma unroll
    for (int e = 0; e < 4; ++e) {
      int k = q * 4 + e;
      float p = v[k] * is1 + 1e-9f;                    // softmax + 1e-9
      float g = -logf(-logf(ua[e] + 1e-20f) + 1e-20f); // gumbel (precise logs)
      v[k] = (logf(p) + g) * 2.0f;                     // (log p + g)/0.5
      m2 = fmaxf(m2, v[k]);
    }
  }
  m2 = blockMax(m2, shf);
  float s2 = 0.f;
#pragma unroll
  for (int k = 0; k < 16; ++k) { v[k] = __expf(v[k] - m2); s2 += v[k]; }
  s2 = blockSum(s2, shf);
  float is2 = 1.0f / s2;
  float bv = -3.4e38f; int bi = 0x7fffffff;
  float* so = out + O_SOFT + (size_t)row * S_ + (size_t)t * 16;
#pragma unroll
  for (int q = 0; q < 4; ++q) {
    float pe[4];
#pragma unroll
    for (int e = 0; e < 4; ++e) {
      int k = q * 4 + e;
      pe[e] = v[k] * is2;
      if (pe[e] > bv) { bv = pe[e]; bi = t * 16 + k; } // ascending j: > keeps first
    }
    float4 pv; pv.x = pe[0]; pv.y = pe[1]; pv.z = pe[2]; pv.w = pe[3];
    ((float4*)so)[q] = pv;
  }
  blockArgmax(bv, bi, shf, shi);
  float* ho = out + O_HARD + (size_t)row * S_ + (size_t)t * 16;
#pragma unroll
  for (int q = 0; q < 4; ++q) {
    float4 hv;
    hv.x = (t * 16 + q * 4 + 0 == bi) ? 1.f : 0.f;
    hv.y = (t * 16 + q * 4 + 1 == bi) ? 1.f : 0.f;
    hv.z = (t * 16 + q * 4 + 2 == bi) ? 1.f : 0.f;
    hv.w = (t * 16 + q * 4 + 3 == bi) ? 1.f : 0.f;
    ((float4*)ho)[q] = hv;
  }

  // ---- coarse tail (ky): all threads hold bi == fine index ----
  float lc = 0.5f * (lzy[(size_t)row * Y_ + t] + lsy[(size_t)bi * Y_ + t]);
  float cm1 = blockMax(lc, shf);
  float ce = __expf(lc - cm1);
  float cs1 = blockSum(ce, shf);
  float cp = ce / cs1 + 1e-9f;
  float cg = -logf(-logf(uy[(size_t)row * Y_ + t] + 1e-20f) + 1e-20f);
  float ca = (logf(cp) + cg) * 2.0f;
  float cm2 = blockMax(ca, shf);
  float cy = __expf(ca - cm2);
  float cs2 = blockSum(cy, shf);
  float csp = cy / cs2;
  out[O_SOFTY + (size_t)row * Y_ + t] = csp;
  float cbv = csp; int cbi = t;
  blockArgmax(cbv, cbi, shf, shi);
  if (t == 0) out[O_BY + row] = (float)cbi;
}

// ---------------------------------------------------------------------------
// launch
// ---------------------------------------------------------------------------
extern "C" void kernel_launch(void* const* d_in, const int* in_sizes, int n_in,
                              void* d_out, int out_size, void* d_ws, size_t ws_size,
                              hipStream_t stream) {
  const float* X    = (const float*)d_in[0];
  const float* W1   = (const float*)d_in[1];
  const float* b1   = (const float*)d_in[2];
  const float* W2   = (const float*)d_in[3];
  const float* b2   = (const float*)d_in[4];
  const float* Ws1  = (const float*)d_in[5];
  const float* bs1  = (const float*)d_in[6];
  const float* Ws2  = (const float*)d_in[7];
  const float* bs2  = (const float*)d_in[8];
  const float* mu_y = (const float*)d_in[9];
  const float* mu_s = (const float*)d_in[10];
  const float* eps  = (const float*)d_in[11];
  const float* u_s  = (const float*)d_in[12];
  const float* u_y  = (const float*)d_in[13];
  float* out = (float*)d_out;   // OUTPUT dtype is FLOAT32

  // ---- workspace layout (peak 151.6 MB; ws >= 164 MB verified in R4) ----
  // Region A [0, 125.83 MB): encoder temporaries, dead after kz.
  // After kz, A-span reuse: LZY@0 (8192x256 f32) | LSY (4096x256 f32) contiguous.
  // Raw fine LOGITS live in d_out's soft_prob slot (overwritten by ks).
  char* ws = (char*)d_ws;
  _Float16* XH    = (_Float16*)(ws + 0);            //  8,388,608
  _Float16* XL    = (_Float16*)(ws + 8388608);
  _Float16* W1CH  = (_Float16*)(ws + 16777216);     //  2,097,152  [2048][512] cat(W1T,Ws1T)
  _Float16* W1CL  = (_Float16*)(ws + 18874368);
  _Float16* W2CH  = (_Float16*)(ws + 20971520);     //  2,097,152  [1024][1024] cat(W2T,Ws2T)
  _Float16* W2CL  = (_Float16*)(ws + 23068672);
  _Float16* H1H   = (_Float16*)(ws + 25165824);     // 33,554,432  [8192][2048]
  _Float16* H1L   = (_Float16*)(ws + 58720256);
  float*    MPS   = (float*)  (ws + 92274688);      // 33,554,432  [8192][1024] = [mu|ps]
  float*    LZY   = (float*)  (ws + 0);             //  8,388,608 (post-kz reuse)
  // (LSY = LZY + B_*Y_ implicitly, contiguous)
  // Region B @125.83 MB (live across dist GEMMs + routing).
  // [ZH|MSH] and [ZL|MSL] contiguous -> coarse-GEMM A is one 12288x512 matrix.
  // [Z2|CS2] contiguous -> coarse-GEMM rown is one 12288-vector.
  const size_t RB = 125829120;
  _Float16* ZH   = (_Float16*)(ws + RB + 0);         //  8,388,608
  _Float16* MSH  = (_Float16*)(ws + RB + 8388608);   //  4,194,304
  _Float16* ZL   = (_Float16*)(ws + RB + 12582912);  //  8,388,608
  _Float16* MSL  = (_Float16*)(ws + RB + 20971520);  //  4,194,304
  _Float16* MYH  = (_Float16*)(ws + RB + 25165824);  //    262,144
  _Float16* MYL  = (_Float16*)(ws + RB + 25427968);  //    262,144
  float*    Z2   = (float*)  (ws + RB + 25690112);   //     32,768
  float*    CS2  = (float*)  (ws + RB + 25722880);   //     16,384 (contiguous after Z2)
  float*    CY2  = (float*)  (ws + RB + 25739264);   //      4,096 -> end 151,572,480
  (void)ws_size; (void)in_sizes; (void)n_in; (void)out_size;

  float* LOGITS = out + O_SOFT;  // raw fine logits staged in the soft_prob slot
  float* LSY = LZY + (size_t)B_ * Y_;

  // 1) prep: X split + weight transpose-splits (L1's direct dependencies)
  prep_kernel<<<2560, 256, 0, stream>>>(X, W1, Ws1, W2, Ws2,
                                        XH, XL, W1CH, W1CL, W2CH, W2CL);

  // 2) L1 GEMM + absorbed prep-B (mu_s/mu_y splits + rownorms) tail blocks
  k_l1<<<2384, 256, 0, stream>>>(XH, XL, W1CH, W1CL, b1, bs1, H1H, H1L,
                                 mu_s, mu_y, MSH, MSL, MYH, MYL, CS2, CY2);

  // 3) L2 GEMM (fused heads: N = 1024 = cat(mu, ps); A-col switch at 512)
  k_l2<<<512, 256, 0, stream>>>(H1H, H1L, W2CH, W2CL, b2, bs2, MPS);

  // 4) reparameterize (region A dead after this)
  kz_kernel<<<B_, 256, 0, stream>>>(MPS, eps, out, ZH, ZL, Z2);

  // 5) merged dist GEMM: fine logits -> out soft slot; coarse -> [LZY|LSY]
  k_dist<<<2240, 256, 0, stream>>>(ZH, ZL, MSH, MSL, MYH, MYL,
                                   LOGITS, LZY, Z2, CS2, CY2);

  // 6) fused fine+coarse routing
  ks_kernel<<<B_, 256, 0, stream>>>(u_s, LZY, LSY, u_y, out);
}